// Round 3
// baseline (184.040 us; speedup 1.0000x reference)
//
#include <hip/hip_runtime.h>
#include <math.h>

#define NPTS 16384
#define KNB  16
#define D    512

// ---------------------------------------------------------------------------
// Closed-form restructure (verified rounds 1-12, absmax 0.0625). With
// S = gather-mean, R = Wres^T + I, M' = (W2c*W1)^T, per-block map
// f' = Cb + S^2 f M' + f R (f0 = 0), tracked in [33,512] coefficient space
// (rows 4k+c = component c of s_k, row 32 = bias):
//   F_1 = Cb33,   F_{t+1} = Cb33 + Shift2(F_t)*M' + F_t*R,   Ecat = F_4
// Final: out = [s0..s7,1] ([N,33]) x Ecat.
// Round 16: prep was ~35-45us of pure critical path (round-1 arithmetic:
// prep+out+gaps = 87us). Split it: prep_a = knn+geo only (reuses the loaded
// knn value for geo — one pass over raw). Mt/Rm/zbuf move INTO H1 as extra
// blocks (hop1 has no dependency on them); fsteps shift to H2/H3/H4.
// Mt flipped for coalesced float2 writes (a wave-uniform -> w_mlp1 scalar
// broadcast, w_mlp2 per-lane row streams). Rm = LDS tile transpose
// ([64][65], conflict-free). zbuf keeps verified wave-per-column form as
// 32 blocks. H1 = 256 hop + 128 Mt + 64 Rm + 32 zbuf = 480 blocks <= 512
// (2 blk/CU @ 64 VGPR) — single scheduling round (in-kernel device barriers
// cost ~70us on 8-XCD MI355X — never again).
// ---------------------------------------------------------------------------

// 1-hop gather-mean, 16 threads/point, 1 neighbor each, t < 262144
__device__ __forceinline__ void onehop16(int t, const int* __restrict__ knn,
                                         const float4* __restrict__ in,
                                         float4* __restrict__ out) {
  int n = t >> 4, k = t & 15;
  float4 g = in[knn[t]];  // knn layout is exactly n*16+k == t
  float ax = g.x, ay = g.y, az = g.z, aw = g.w;
#pragma unroll
  for (int o = 1; o < 16; o <<= 1) {
    ax += __shfl_xor(ax, o, 64); ay += __shfl_xor(ay, o, 64);
    az += __shfl_xor(az, o, 64); aw += __shfl_xor(aw, o, 64);
  }
  if (k == 0) {
    const float r = 1.f / 16.f;
    out[n] = make_float4(ax * r, ay * r, az * r, aw * r);
  }
}

__device__ __forceinline__ float4 red16(float ax, float ay, float az,
                                        float aw) {
#pragma unroll
  for (int o = 1; o < 16; o <<= 1) {
    ax += __shfl_xor(ax, o, 64); ay += __shfl_xor(ay, o, 64);
    az += __shfl_xor(az, o, 64); aw += __shfl_xor(aw, o, 64);
  }
  return make_float4(ax, ay, az, aw);
}

// One Horner step, 66 blocks: block fb -> row r = fb>>1, cols
// jbase..jbase+255 (jbase = (fb&1)*256). Threads: 64 col-quads x 16 k-chunks
// of 32. float4 loads of Rm/Mt (1KB/wave-inst), acc[4] fp64 per thread,
// LDS reduce over k-chunks. fp64 accumulate (verified numerics).
__device__ __forceinline__ void fstep66(
    int fb, int tid, int first, const float* __restrict__ Fprev,
    const float* __restrict__ zbuf, const float* __restrict__ Rm,
    const float* __restrict__ Mt, float* __restrict__ Fnext) {
  __shared__ float sA[512], sB[512];
  __shared__ double redm[16][256];
  const int r = fb >> 1, jbase = (fb & 1) * 256;
  const int rm = (r >= 8 && r < 32) ? (r - 8) : (r == 32 ? 32 : -1);
  if (tid < 512) {
    sA[tid] = first
        ? ((r < 8) ? zbuf[r * D + tid] : (r == 32 ? zbuf[8 * D + tid] : 0.f))
        : Fprev[r * D + tid];
  } else {
    int kk = tid - 512;
    float v = 0.f;
    if (rm >= 0)
      v = first ? ((rm < 8) ? zbuf[rm * D + kk]
                            : (rm == 32 ? zbuf[8 * D + kk] : 0.f))
                : Fprev[rm * D + kk];
    sB[kk] = v;
  }
  __syncthreads();
  const int q = tid & 63, kc = tid >> 6;   // col-quad, k-chunk
  const int j0 = jbase + q * 4, k0 = kc * 32;
  double a0 = 0, a1 = 0, a2 = 0, a3 = 0;
#pragma unroll 2
  for (int k = 0; k < 32; ++k) {
    const float4 rv = *(const float4*)(Rm + (size_t)(k0 + k) * D + j0);
    const float4 mv = *(const float4*)(Mt + (size_t)(k0 + k) * D + j0);
    const double a = (double)sA[k0 + k], b = (double)sB[k0 + k];
    a0 += a * (double)rv.x + b * (double)mv.x;
    a1 += a * (double)rv.y + b * (double)mv.y;
    a2 += a * (double)rv.z + b * (double)mv.z;
    a3 += a * (double)rv.w + b * (double)mv.w;
  }
  redm[kc][q * 4 + 0] = a0; redm[kc][q * 4 + 1] = a1;
  redm[kc][q * 4 + 2] = a2; redm[kc][q * 4 + 3] = a3;
  __syncthreads();
  if (tid < 256) {
    double s = 0.0;
#pragma unroll
    for (int u = 0; u < 16; ++u) s += redm[u][tid];
    int j = jbase + tid;
    float cb = (r < 8) ? zbuf[r * D + j] : (r == 32 ? zbuf[8 * D + j] : 0.f);
    Fnext[r * D + j] = (float)(s + (double)cb);
  }
}

// ---- prep_a: knn normalize + geo/s0 only (critical-path minimum) ----
__global__ __launch_bounds__(1024) void prep_a_kernel(
    const float* __restrict__ pts, const int* __restrict__ raw,
    int* __restrict__ knn_i, float4* __restrict__ sbase) {
  // int64 little-endian => odd words are zero high halves
  const bool is64 = (raw[1] == 0) && (raw[3] == 0) && (raw[5] == 0) &&
                    (raw[7] == 0);
  const int t = blockIdx.x * 1024 + threadIdx.x;  // < 262144
  const int idx = is64 ? raw[2 * t] : raw[t];
  knn_i[t] = idx;
  // geo: 16 threads/point; t == n*KNB+k so idx IS this (n,k)'s neighbor
  int n = t >> 4, k = t & 15;
  float dx = pts[n * 3 + 0] - pts[idx * 3 + 0];
  float dy = pts[n * 3 + 1] - pts[idx * 3 + 1];
  float dz = pts[n * 3 + 2] - pts[idx * 3 + 2];
  float nr = sqrtf(dx * dx + dy * dy + dz * dz);
  float4 s = red16(dx, dy, dz, nr);
  if (k == 0) {
    const float r = 1.f / 16.f;
    sbase[n] = make_float4(s.x * r, s.y * r, s.z * r, s.w * r);
  }
}

// ---- H1: hop1 (256) | Mt (128, coalesced writes) | Rm (64, LDS transpose)
//      | zbuf (32, wave-per-column) = 480 blocks ----
__global__ __launch_bounds__(1024, 8) void hprep_kernel(
    const int* __restrict__ knn, const float4* __restrict__ sin,
    float4* __restrict__ sout,
    const float* __restrict__ w_mlp1, const float* __restrict__ b_mlp1,
    const float* __restrict__ w_lfa1, const float* __restrict__ b_lfa1,
    const float* __restrict__ w_lfa2, const float* __restrict__ b_lfa2,
    const float* __restrict__ w_mlp2, const float* __restrict__ b_mlp2,
    const float* __restrict__ w_res, const float* __restrict__ b_res,
    float* __restrict__ zbuf, float* __restrict__ Mt,
    float* __restrict__ Rm) {
  const int tid = threadIdx.x;
  const int blk = blockIdx.x;
  if (blk < 256) {  // hop1
    onehop16(blk * 1024 + tid, knn, sin, sout);
  } else if (blk < 384) {  // Mt: thread -> 2 consecutive outputs, coalesced
    // Mt[a*D+b] = sum_{i<128} w_mlp2[b][384+i] * w_mlp1[i][a]
    int m = (blk - 256) * 1024 + tid;        // [0, 131072)
    int t2 = m * 2;
    int a = t2 >> 9;                          // wave-uniform
    int b0 = t2 & 511;
    const float* r0 = w_mlp2 + (size_t)b0 * D + 384;
    const float* r1 = r0 + D;
    double s00 = 0, s01 = 0, s10 = 0, s11 = 0;
#pragma unroll 8
    for (int i = 0; i < 128; i += 2) {
      double wa0 = (double)w_mlp1[(size_t)i * D + a];
      double wa1 = (double)w_mlp1[(size_t)(i + 1) * D + a];
      s00 += (double)r0[i] * wa0; s01 += (double)r0[i + 1] * wa1;
      s10 += (double)r1[i] * wa0; s11 += (double)r1[i + 1] * wa1;
    }
    float2 o;
    o.x = (float)(s00 + s01);
    o.y = (float)(s10 + s11);
    *(float2*)(Mt + t2) = o;
  } else if (blk < 448) {  // Rm: 64x64 LDS tile transpose, conflict-free
    __shared__ float tr[64][65];
    int tile = blk - 384, ti = tile & 7, tj = tile >> 3;
    int I0 = ti * 64, J0 = tj * 64;           // i-range, j-range
    int c = tid & 63, r4 = tid >> 6;          // 16 rows/pass
#pragma unroll
    for (int u = 0; u < 4; ++u) {
      int row = u * 16 + r4;
      tr[row][c] = w_res[(size_t)(J0 + row) * D + I0 + c];
    }
    __syncthreads();
#pragma unroll
    for (int u = 0; u < 4; ++u) {
      int row = u * 16 + r4;
      int i = I0 + row, j = J0 + c;
      Rm[(size_t)i * D + j] = tr[c][row] + ((i == j) ? 1.0f : 0.0f);
    }
  } else {  // zbuf: wave-per-column, fp64 accumulate (verified form)
    int t = (blk - 448) * 1024 + tid;         // < 32768
    int j = t >> 6, lane = t & 63;
    const float* wrow = w_mlp2 + (size_t)j * D;
    double acc[9];
#pragma unroll
    for (int u = 0; u < 9; ++u) acc[u] = 0.0;
#pragma unroll
    for (int it = 0; it < 8; ++it) {
      int i = lane + 64 * it;
      double w = wrow[i];
      if (i < 256) {
        acc[0] += w * w_lfa2[i * 4 + 0]; acc[1] += w * w_lfa2[i * 4 + 1];
        acc[2] += w * w_lfa2[i * 4 + 2]; acc[3] += w * w_lfa2[i * 4 + 3];
        acc[8] += w * b_lfa2[i];
      } else if (i < 384) {
        int q = i - 256;
        acc[4] += w * w_lfa1[q * 4 + 0]; acc[5] += w * w_lfa1[q * 4 + 1];
        acc[6] += w * w_lfa1[q * 4 + 2]; acc[7] += w * w_lfa1[q * 4 + 3];
        acc[8] += w * b_lfa1[q];
      } else {
        acc[8] += w * b_mlp1[i - 384];
      }
    }
#pragma unroll
    for (int u = 0; u < 9; ++u) {
      double v = acc[u];
#pragma unroll
      for (int o = 32; o > 0; o >>= 1) v += __shfl_down(v, o, 64);
      if (lane == 0) {
        if (u == 8) v += (double)b_mlp2[j] + (double)b_res[j];
        zbuf[u * D + j] = (float)v;
      }
    }
  }
}

// ---- combined: blocks [0,256) 1-hop (16 thr/pt), [256,322) fstep66 ----
__global__ __launch_bounds__(1024, 8) void hopf_kernel(
    const int* __restrict__ knn, const float4* __restrict__ sin,
    float4* __restrict__ sout, const float* __restrict__ zbuf,
    const float* __restrict__ Rm, const float* __restrict__ Mt,
    const float* __restrict__ Fprev, float* __restrict__ Fnext, int first) {
  const int tid = threadIdx.x;
  if (blockIdx.x < 256) {
    onehop16(blockIdx.x * 1024 + tid, knn, sin, sout);
  } else {
    fstep66((int)blockIdx.x - 256, tid, first, Fprev, zbuf, Rm, Mt, Fnext);
  }
}

// ---- pure 1-hop: 256 blocks, 16 thr/pt, no LDS ----
__global__ __launch_bounds__(1024, 8) void hop_kernel(
    const int* __restrict__ knn, const float4* __restrict__ sin,
    float4* __restrict__ sout) {
  onehop16(blockIdx.x * 1024 + threadIdx.x, knn, sin, sout);
}

// ---- L4: out[n][:] = [s0..s7,1][n] x Ecat; s7 inline (1-hop from s6) ----
__global__ __launch_bounds__(1024, 4) void out_kernel(
    const int* __restrict__ knn, const float4* __restrict__ sbase,
    const float* __restrict__ Ecat, float* __restrict__ outp) {
  const int tid = threadIdx.x;
  const int n0 = blockIdx.x * 64;
  __shared__ float4 s_t[8][64];
  {  // s7 for this block's 64 points: 16 threads/point
    int pt = tid >> 4, k = tid & 15;
    float4 g = sbase[(size_t)6 * NPTS + knn[(n0 + pt) * KNB + k]];
    float4 s = red16(g.x, g.y, g.z, g.w);
    if (k == 0) {
      const float r = 1.f / 16.f;
      s_t[7][pt] = make_float4(s.x * r, s.y * r, s.z * r, s.w * r);
    }
  }
  if (tid < 448) {  // load s0..s6 tiles
    int k = tid / 64, pt = tid & 63;
    s_t[k][pt] = sbase[(size_t)k * NPTS + n0 + pt];
  }
  __syncthreads();
  const int col2 = tid & 255;  // this thread's float2 column
  const int ptg = tid >> 8;    // 0..3
  float2 tab[33];
#pragma unroll
  for (int r = 0; r < 33; ++r)
    tab[r] = *(const float2*)(Ecat + r * D + col2 * 2);
#pragma unroll
  for (int it = 0; it < 16; ++it) {
    int pt = ptg * 16 + it;
    float2 acc = tab[32];
#pragma unroll
    for (int k = 0; k < 8; ++k) {
      float4 s = s_t[k][pt];  // wave-uniform LDS broadcast
      float2 e0 = tab[4 * k + 0], e1 = tab[4 * k + 1];
      float2 e2 = tab[4 * k + 2], e3 = tab[4 * k + 3];
      acc.x += s.x * e0.x + s.y * e1.x + s.z * e2.x + s.w * e3.x;
      acc.y += s.x * e0.y + s.y * e1.y + s.z * e2.y + s.w * e3.y;
    }
    *(float2*)(outp + (size_t)(n0 + pt) * D + col2 * 2) = acc;
  }
}

extern "C" void kernel_launch(void* const* d_in, const int* in_sizes, int n_in,
                              void* d_out, int out_size, void* d_ws,
                              size_t ws_size, hipStream_t stream) {
  const float* inputs = (const float*)d_in[0];
  const int* knn_raw  = (const int*)d_in[1];
  const float* w_mlp1 = (const float*)d_in[2];
  const float* b_mlp1 = (const float*)d_in[3];
  const float* w_lfa1 = (const float*)d_in[4];
  const float* b_lfa1 = (const float*)d_in[5];
  const float* w_lfa2 = (const float*)d_in[6];
  const float* b_lfa2 = (const float*)d_in[7];
  const float* w_mlp2 = (const float*)d_in[8];
  const float* b_mlp2 = (const float*)d_in[9];
  const float* w_res  = (const float*)d_in[10];
  const float* b_res  = (const float*)d_in[11];
  float* out = (float*)d_out;

  // workspace (floats): ~5.5 MB
  float*  ws    = (float*)d_ws;
  float4* sbase = (float4*)(ws + 0);          // 8 * 16384 float4
  float*  zbuf  = ws + 524288;                // 9 * 512
  float*  F2    = ws + 528896;                // 33 * 512
  float*  F3    = ws + 545792;                // 33 * 512
  float*  Ecat  = ws + 562688;                // 33 * 512
  int*    knn_i = (int*)(ws + 579584);        // 262144 ints
  float*  Mt    = ws + 841728;                // 262144 floats
  float*  Rm    = ws + 1103872;               // 262144 floats

  float4* s0 = (float4*)sbase;
  // prep_a: knn + geo/s0 only
  prep_a_kernel<<<256, 1024, 0, stream>>>(inputs, knn_raw, knn_i, sbase);
  // H1: s1 = S s0 | Mt | Rm | zbuf
  hprep_kernel<<<480, 1024, 0, stream>>>(knn_i, s0, s0 + NPTS,
                                         w_mlp1, b_mlp1, w_lfa1, b_lfa1,
                                         w_lfa2, b_lfa2, w_mlp2, b_mlp2,
                                         w_res, b_res, zbuf, Mt, Rm);
  // H2: s2 = S s1 | fstep1: F2 = step(Cb)
  hopf_kernel<<<322, 1024, 0, stream>>>(knn_i, s0 + NPTS, s0 + 2 * NPTS, zbuf,
                                        Rm, Mt, (const float*)nullptr, F2, 1);
  // H3: s3 = S s2 | fstep2: F3 = step(F2)
  hopf_kernel<<<322, 1024, 0, stream>>>(knn_i, s0 + 2 * NPTS, s0 + 3 * NPTS,
                                        zbuf, Rm, Mt, F2, F3, 0);
  // H4: s4 = S s3 | fstep3: Ecat = F4 = step(F3)
  hopf_kernel<<<322, 1024, 0, stream>>>(knn_i, s0 + 3 * NPTS, s0 + 4 * NPTS,
                                        zbuf, Rm, Mt, F3, Ecat, 0);
  // H5: s5 = S s4
  hop_kernel<<<256, 1024, 0, stream>>>(knn_i, s0 + 4 * NPTS, s0 + 5 * NPTS);
  // H6: s6 = S s5
  hop_kernel<<<256, 1024, 0, stream>>>(knn_i, s0 + 5 * NPTS, s0 + 6 * NPTS);
  // L4: out (s7 inline)
  out_kernel<<<256, 1024, 0, stream>>>(knn_i, sbase, Ecat, out);
}

// Round 4
// 168.581 us; speedup vs baseline: 1.0917x; 1.0917x over previous
//
#include <hip/hip_runtime.h>
#include <math.h>

#define NPTS 16384
#define KNB  16
#define D    512

// ---------------------------------------------------------------------------
// Closed-form restructure (verified rounds 1-12, absmax 0.0625). With
// S = gather-mean, R = Wres^T + I, M' = (W2c*W1)^T, per-block map
// f' = Cb + S^2 f M' + f R (f0 = 0), tracked in [33,512] coefficient space
// (rows 4k+c = component c of s_k, row 32 = bias):
//   F_1 = Cb33,   F_{t+1} = Cb33 + Shift2(F_t)*M' + F_t*R,   Ecat = F_4
// Final: out = [s0..s7,1] ([N,33]) x Ecat.
// Round 17: round-16's Mt rewrite made per-lane 2KB-strided READS of w_mlp2
// (64 lines/wave-load, ~33M L1 transactions -> hprep=146us, everything idle).
// Lesson: coalesce/broadcast the READS, scatter the WRITES (0.26M write
// transactions are cheap). Mt now: a per-lane (w_mlp1 coalesced), 4
// consecutive b per thread (w_mlp2 rows wave-uniform -> broadcast), output
// one contiguous float4 store Mt[a*D+b0..3]. 64 blocks. Schedule unchanged:
// prep_a = knn+geo only; H1 = 256 hop + 64 Mt + 64 Rm + 32 zbuf = 416
// blocks <= 512 (2 blk/CU @ 64 VGPR) — single scheduling round (in-kernel
// device barriers cost ~70us on 8-XCD MI355X — never again).
// ---------------------------------------------------------------------------

// 1-hop gather-mean, 16 threads/point, 1 neighbor each, t < 262144
__device__ __forceinline__ void onehop16(int t, const int* __restrict__ knn,
                                         const float4* __restrict__ in,
                                         float4* __restrict__ out) {
  int n = t >> 4, k = t & 15;
  float4 g = in[knn[t]];  // knn layout is exactly n*16+k == t
  float ax = g.x, ay = g.y, az = g.z, aw = g.w;
#pragma unroll
  for (int o = 1; o < 16; o <<= 1) {
    ax += __shfl_xor(ax, o, 64); ay += __shfl_xor(ay, o, 64);
    az += __shfl_xor(az, o, 64); aw += __shfl_xor(aw, o, 64);
  }
  if (k == 0) {
    const float r = 1.f / 16.f;
    out[n] = make_float4(ax * r, ay * r, az * r, aw * r);
  }
}

__device__ __forceinline__ float4 red16(float ax, float ay, float az,
                                        float aw) {
#pragma unroll
  for (int o = 1; o < 16; o <<= 1) {
    ax += __shfl_xor(ax, o, 64); ay += __shfl_xor(ay, o, 64);
    az += __shfl_xor(az, o, 64); aw += __shfl_xor(aw, o, 64);
  }
  return make_float4(ax, ay, az, aw);
}

// One Horner step, 66 blocks: block fb -> row r = fb>>1, cols
// jbase..jbase+255 (jbase = (fb&1)*256). Threads: 64 col-quads x 16 k-chunks
// of 32. float4 loads of Rm/Mt (1KB/wave-inst), acc[4] fp64 per thread,
// LDS reduce over k-chunks. fp64 accumulate (verified numerics).
__device__ __forceinline__ void fstep66(
    int fb, int tid, int first, const float* __restrict__ Fprev,
    const float* __restrict__ zbuf, const float* __restrict__ Rm,
    const float* __restrict__ Mt, float* __restrict__ Fnext) {
  __shared__ float sA[512], sB[512];
  __shared__ double redm[16][256];
  const int r = fb >> 1, jbase = (fb & 1) * 256;
  const int rm = (r >= 8 && r < 32) ? (r - 8) : (r == 32 ? 32 : -1);
  if (tid < 512) {
    sA[tid] = first
        ? ((r < 8) ? zbuf[r * D + tid] : (r == 32 ? zbuf[8 * D + tid] : 0.f))
        : Fprev[r * D + tid];
  } else {
    int kk = tid - 512;
    float v = 0.f;
    if (rm >= 0)
      v = first ? ((rm < 8) ? zbuf[rm * D + kk]
                            : (rm == 32 ? zbuf[8 * D + kk] : 0.f))
                : Fprev[rm * D + kk];
    sB[kk] = v;
  }
  __syncthreads();
  const int q = tid & 63, kc = tid >> 6;   // col-quad, k-chunk
  const int j0 = jbase + q * 4, k0 = kc * 32;
  double a0 = 0, a1 = 0, a2 = 0, a3 = 0;
#pragma unroll 2
  for (int k = 0; k < 32; ++k) {
    const float4 rv = *(const float4*)(Rm + (size_t)(k0 + k) * D + j0);
    const float4 mv = *(const float4*)(Mt + (size_t)(k0 + k) * D + j0);
    const double a = (double)sA[k0 + k], b = (double)sB[k0 + k];
    a0 += a * (double)rv.x + b * (double)mv.x;
    a1 += a * (double)rv.y + b * (double)mv.y;
    a2 += a * (double)rv.z + b * (double)mv.z;
    a3 += a * (double)rv.w + b * (double)mv.w;
  }
  redm[kc][q * 4 + 0] = a0; redm[kc][q * 4 + 1] = a1;
  redm[kc][q * 4 + 2] = a2; redm[kc][q * 4 + 3] = a3;
  __syncthreads();
  if (tid < 256) {
    double s = 0.0;
#pragma unroll
    for (int u = 0; u < 16; ++u) s += redm[u][tid];
    int j = jbase + tid;
    float cb = (r < 8) ? zbuf[r * D + j] : (r == 32 ? zbuf[8 * D + j] : 0.f);
    Fnext[r * D + j] = (float)(s + (double)cb);
  }
}

// ---- prep_a: knn normalize + geo/s0 only (critical-path minimum) ----
__global__ __launch_bounds__(1024) void prep_a_kernel(
    const float* __restrict__ pts, const int* __restrict__ raw,
    int* __restrict__ knn_i, float4* __restrict__ sbase) {
  // int64 little-endian => odd words are zero high halves
  const bool is64 = (raw[1] == 0) && (raw[3] == 0) && (raw[5] == 0) &&
                    (raw[7] == 0);
  const int t = blockIdx.x * 1024 + threadIdx.x;  // < 262144
  const int idx = is64 ? raw[2 * t] : raw[t];
  knn_i[t] = idx;
  // geo: 16 threads/point; t == n*KNB+k so idx IS this (n,k)'s neighbor
  int n = t >> 4, k = t & 15;
  float dx = pts[n * 3 + 0] - pts[idx * 3 + 0];
  float dy = pts[n * 3 + 1] - pts[idx * 3 + 1];
  float dz = pts[n * 3 + 2] - pts[idx * 3 + 2];
  float nr = sqrtf(dx * dx + dy * dy + dz * dz);
  float4 s = red16(dx, dy, dz, nr);
  if (k == 0) {
    const float r = 1.f / 16.f;
    sbase[n] = make_float4(s.x * r, s.y * r, s.z * r, s.w * r);
  }
}

// ---- H1: hop1 (256) | Mt (64, coalesced/broadcast reads, float4 store)
//      | Rm (64, LDS transpose) | zbuf (32, wave-per-column) = 416 blocks ----
__global__ __launch_bounds__(1024, 8) void hprep_kernel(
    const int* __restrict__ knn, const float4* __restrict__ sin,
    float4* __restrict__ sout,
    const float* __restrict__ w_mlp1, const float* __restrict__ b_mlp1,
    const float* __restrict__ w_lfa1, const float* __restrict__ b_lfa1,
    const float* __restrict__ w_lfa2, const float* __restrict__ b_lfa2,
    const float* __restrict__ w_mlp2, const float* __restrict__ b_mlp2,
    const float* __restrict__ w_res, const float* __restrict__ b_res,
    float* __restrict__ zbuf, float* __restrict__ Mt,
    float* __restrict__ Rm) {
  const int tid = threadIdx.x;
  const int blk = blockIdx.x;
  if (blk < 256) {  // hop1
    onehop16(blk * 1024 + tid, knn, sin, sout);
  } else if (blk < 320) {
    // Mt[a*D+b] = sum_{i<128} w_mlp2[b][384+i] * w_mlp1[i][a]
    // a per-lane (w_mlp1 coalesced), 4 consecutive b per thread (w_mlp2
    // rows wave-uniform -> broadcast), one float4 store.
    int m = (blk - 256) * 1024 + tid;         // [0, 65536)
    int a = m & 511;                          // per-lane, consecutive
    int b0 = (m >> 9) * 4;                    // wave-uniform, 0..508
    const float* r0 = w_mlp2 + (size_t)(b0 + 0) * D + 384;
    const float* r1 = w_mlp2 + (size_t)(b0 + 1) * D + 384;
    const float* r2 = w_mlp2 + (size_t)(b0 + 2) * D + 384;
    const float* r3 = w_mlp2 + (size_t)(b0 + 3) * D + 384;
    double s0a = 0, s0b = 0, s1a = 0, s1b = 0;
    double s2a = 0, s2b = 0, s3a = 0, s3b = 0;
#pragma unroll 4
    for (int i = 0; i < 128; i += 2) {
      double wa0 = (double)w_mlp1[(size_t)i * D + a];
      double wa1 = (double)w_mlp1[(size_t)(i + 1) * D + a];
      s0a += (double)r0[i] * wa0; s0b += (double)r0[i + 1] * wa1;
      s1a += (double)r1[i] * wa0; s1b += (double)r1[i + 1] * wa1;
      s2a += (double)r2[i] * wa0; s2b += (double)r2[i + 1] * wa1;
      s3a += (double)r3[i] * wa0; s3b += (double)r3[i + 1] * wa1;
    }
    float4 o;
    o.x = (float)(s0a + s0b); o.y = (float)(s1a + s1b);
    o.z = (float)(s2a + s2b); o.w = (float)(s3a + s3b);
    *(float4*)(Mt + (size_t)a * D + b0) = o;
  } else if (blk < 384) {  // Rm: 64x64 LDS tile transpose, conflict-free
    __shared__ float tr[64][65];
    int tile = blk - 320, ti = tile & 7, tj = tile >> 3;
    int I0 = ti * 64, J0 = tj * 64;           // i-range, j-range
    int c = tid & 63, r4 = tid >> 6;          // 16 rows/pass
#pragma unroll
    for (int u = 0; u < 4; ++u) {
      int row = u * 16 + r4;
      tr[row][c] = w_res[(size_t)(J0 + row) * D + I0 + c];
    }
    __syncthreads();
#pragma unroll
    for (int u = 0; u < 4; ++u) {
      int row = u * 16 + r4;
      int i = I0 + row, j = J0 + c;
      Rm[(size_t)i * D + j] = tr[c][row] + ((i == j) ? 1.0f : 0.0f);
    }
  } else {  // zbuf: wave-per-column, fp64 accumulate (verified form)
    int t = (blk - 384) * 1024 + tid;         // < 32768
    int j = t >> 6, lane = t & 63;
    const float* wrow = w_mlp2 + (size_t)j * D;
    double acc[9];
#pragma unroll
    for (int u = 0; u < 9; ++u) acc[u] = 0.0;
#pragma unroll
    for (int it = 0; it < 8; ++it) {
      int i = lane + 64 * it;
      double w = wrow[i];
      if (i < 256) {
        acc[0] += w * w_lfa2[i * 4 + 0]; acc[1] += w * w_lfa2[i * 4 + 1];
        acc[2] += w * w_lfa2[i * 4 + 2]; acc[3] += w * w_lfa2[i * 4 + 3];
        acc[8] += w * b_lfa2[i];
      } else if (i < 384) {
        int q = i - 256;
        acc[4] += w * w_lfa1[q * 4 + 0]; acc[5] += w * w_lfa1[q * 4 + 1];
        acc[6] += w * w_lfa1[q * 4 + 2]; acc[7] += w * w_lfa1[q * 4 + 3];
        acc[8] += w * b_lfa1[q];
      } else {
        acc[8] += w * b_mlp1[i - 384];
      }
    }
#pragma unroll
    for (int u = 0; u < 9; ++u) {
      double v = acc[u];
#pragma unroll
      for (int o = 32; o > 0; o >>= 1) v += __shfl_down(v, o, 64);
      if (lane == 0) {
        if (u == 8) v += (double)b_mlp2[j] + (double)b_res[j];
        zbuf[u * D + j] = (float)v;
      }
    }
  }
}

// ---- combined: blocks [0,256) 1-hop (16 thr/pt), [256,322) fstep66 ----
__global__ __launch_bounds__(1024, 8) void hopf_kernel(
    const int* __restrict__ knn, const float4* __restrict__ sin,
    float4* __restrict__ sout, const float* __restrict__ zbuf,
    const float* __restrict__ Rm, const float* __restrict__ Mt,
    const float* __restrict__ Fprev, float* __restrict__ Fnext, int first) {
  const int tid = threadIdx.x;
  if (blockIdx.x < 256) {
    onehop16(blockIdx.x * 1024 + tid, knn, sin, sout);
  } else {
    fstep66((int)blockIdx.x - 256, tid, first, Fprev, zbuf, Rm, Mt, Fnext);
  }
}

// ---- pure 1-hop: 256 blocks, 16 thr/pt, no LDS ----
__global__ __launch_bounds__(1024, 8) void hop_kernel(
    const int* __restrict__ knn, const float4* __restrict__ sin,
    float4* __restrict__ sout) {
  onehop16(blockIdx.x * 1024 + threadIdx.x, knn, sin, sout);
}

// ---- L4: out[n][:] = [s0..s7,1][n] x Ecat; s7 inline (1-hop from s6) ----
__global__ __launch_bounds__(1024, 4) void out_kernel(
    const int* __restrict__ knn, const float4* __restrict__ sbase,
    const float* __restrict__ Ecat, float* __restrict__ outp) {
  const int tid = threadIdx.x;
  const int n0 = blockIdx.x * 64;
  __shared__ float4 s_t[8][64];
  {  // s7 for this block's 64 points: 16 threads/point
    int pt = tid >> 4, k = tid & 15;
    float4 g = sbase[(size_t)6 * NPTS + knn[(n0 + pt) * KNB + k]];
    float4 s = red16(g.x, g.y, g.z, g.w);
    if (k == 0) {
      const float r = 1.f / 16.f;
      s_t[7][pt] = make_float4(s.x * r, s.y * r, s.z * r, s.w * r);
    }
  }
  if (tid < 448) {  // load s0..s6 tiles
    int k = tid / 64, pt = tid & 63;
    s_t[k][pt] = sbase[(size_t)k * NPTS + n0 + pt];
  }
  __syncthreads();
  const int col2 = tid & 255;  // this thread's float2 column
  const int ptg = tid >> 8;    // 0..3
  float2 tab[33];
#pragma unroll
  for (int r = 0; r < 33; ++r)
    tab[r] = *(const float2*)(Ecat + r * D + col2 * 2);
#pragma unroll
  for (int it = 0; it < 16; ++it) {
    int pt = ptg * 16 + it;
    float2 acc = tab[32];
#pragma unroll
    for (int k = 0; k < 8; ++k) {
      float4 s = s_t[k][pt];  // wave-uniform LDS broadcast
      float2 e0 = tab[4 * k + 0], e1 = tab[4 * k + 1];
      float2 e2 = tab[4 * k + 2], e3 = tab[4 * k + 3];
      acc.x += s.x * e0.x + s.y * e1.x + s.z * e2.x + s.w * e3.x;
      acc.y += s.x * e0.y + s.y * e1.y + s.z * e2.y + s.w * e3.y;
    }
    *(float2*)(outp + (size_t)(n0 + pt) * D + col2 * 2) = acc;
  }
}

extern "C" void kernel_launch(void* const* d_in, const int* in_sizes, int n_in,
                              void* d_out, int out_size, void* d_ws,
                              size_t ws_size, hipStream_t stream) {
  const float* inputs = (const float*)d_in[0];
  const int* knn_raw  = (const int*)d_in[1];
  const float* w_mlp1 = (const float*)d_in[2];
  const float* b_mlp1 = (const float*)d_in[3];
  const float* w_lfa1 = (const float*)d_in[4];
  const float* b_lfa1 = (const float*)d_in[5];
  const float* w_lfa2 = (const float*)d_in[6];
  const float* b_lfa2 = (const float*)d_in[7];
  const float* w_mlp2 = (const float*)d_in[8];
  const float* b_mlp2 = (const float*)d_in[9];
  const float* w_res  = (const float*)d_in[10];
  const float* b_res  = (const float*)d_in[11];
  float* out = (float*)d_out;

  // workspace (floats): ~5.5 MB
  float*  ws    = (float*)d_ws;
  float4* sbase = (float4*)(ws + 0);          // 8 * 16384 float4
  float*  zbuf  = ws + 524288;                // 9 * 512
  float*  F2    = ws + 528896;                // 33 * 512
  float*  F3    = ws + 545792;                // 33 * 512
  float*  Ecat  = ws + 562688;                // 33 * 512
  int*    knn_i = (int*)(ws + 579584);        // 262144 ints
  float*  Mt    = ws + 841728;                // 262144 floats
  float*  Rm    = ws + 1103872;               // 262144 floats

  float4* s0 = (float4*)sbase;
  // prep_a: knn + geo/s0 only
  prep_a_kernel<<<256, 1024, 0, stream>>>(inputs, knn_raw, knn_i, sbase);
  // H1: s1 = S s0 | Mt | Rm | zbuf
  hprep_kernel<<<416, 1024, 0, stream>>>(knn_i, s0, s0 + NPTS,
                                         w_mlp1, b_mlp1, w_lfa1, b_lfa1,
                                         w_lfa2, b_lfa2, w_mlp2, b_mlp2,
                                         w_res, b_res, zbuf, Mt, Rm);
  // H2: s2 = S s1 | fstep1: F2 = step(Cb)
  hopf_kernel<<<322, 1024, 0, stream>>>(knn_i, s0 + NPTS, s0 + 2 * NPTS, zbuf,
                                        Rm, Mt, (const float*)nullptr, F2, 1);
  // H3: s3 = S s2 | fstep2: F3 = step(F2)
  hopf_kernel<<<322, 1024, 0, stream>>>(knn_i, s0 + 2 * NPTS, s0 + 3 * NPTS,
                                        zbuf, Rm, Mt, F2, F3, 0);
  // H4: s4 = S s3 | fstep3: Ecat = F4 = step(F3)
  hopf_kernel<<<322, 1024, 0, stream>>>(knn_i, s0 + 3 * NPTS, s0 + 4 * NPTS,
                                        zbuf, Rm, Mt, F3, Ecat, 0);
  // H5: s5 = S s4
  hop_kernel<<<256, 1024, 0, stream>>>(knn_i, s0 + 4 * NPTS, s0 + 5 * NPTS);
  // H6: s6 = S s5
  hop_kernel<<<256, 1024, 0, stream>>>(knn_i, s0 + 5 * NPTS, s0 + 6 * NPTS);
  // L4: out (s7 inline)
  out_kernel<<<256, 1024, 0, stream>>>(knn_i, sbase, Ecat, out);
}

// Round 5
// 152.624 us; speedup vs baseline: 1.2058x; 1.1046x over previous
//
#include <hip/hip_runtime.h>
#include <math.h>

#define NPTS 16384
#define KNB  16
#define D    512

// ---------------------------------------------------------------------------
// Closed-form restructure (verified rounds 1-12, absmax 0.0625). With
// S = gather-mean, R = Wres^T + I, M' = (W2c*W1)^T, per-block map
// f' = Cb + S^2 f M' + f R (f0 = 0), tracked in [33,512] coefficient space
// (rows 4k+c = component c of s_k, row 32 = bias):
//   F_1 = Cb33,   F_{t+1} = Cb33 + Shift2(F_t)*M' + F_t*R,   Ecat = F_4
// Final: out = [s0..s7,1] ([N,33]) x Ecat.
// Round 18: revert to round-15 structure (159.4 verified; rounds 16/17's
// prep-split regressed — prep hiding doesn't pay, fixed costs dominate).
// New lever: in hopf dispatches the pace-setter is each fstep66 block
// pulling 1MB of Rm+Mt through ONE CU's L1 (16K line-requests ~ 7us) while
// hop CUs finish in ~1us. Split each fstep block in HALF along k: 132
// blocks x 512KB. Cross-block k-reduce via two fp32 partial buffers
// (Pa,Pb); consumer sums the pair (next fstep's sA/sB load, out's tab
// load). Each half still fp64-accumulated -> one extra f32 add, ulp-level.
// Ecat partials alias F2's (dead after H3). Grids stay <= 512 blocks
// (2 blk/CU) = single scheduling round (in-kernel device barriers cost
// ~70us on 8-XCD MI355X — never again).
// ---------------------------------------------------------------------------

// 1-hop gather-mean, 16 threads/point, 1 neighbor each, t < 262144
__device__ __forceinline__ void onehop16(int t, const int* __restrict__ knn,
                                         const float4* __restrict__ in,
                                         float4* __restrict__ out) {
  int n = t >> 4, k = t & 15;
  float4 g = in[knn[t]];  // knn layout is exactly n*16+k == t
  float ax = g.x, ay = g.y, az = g.z, aw = g.w;
#pragma unroll
  for (int o = 1; o < 16; o <<= 1) {
    ax += __shfl_xor(ax, o, 64); ay += __shfl_xor(ay, o, 64);
    az += __shfl_xor(az, o, 64); aw += __shfl_xor(aw, o, 64);
  }
  if (k == 0) {
    const float r = 1.f / 16.f;
    out[n] = make_float4(ax * r, ay * r, az * r, aw * r);
  }
}

__device__ __forceinline__ float4 red16(float ax, float ay, float az,
                                        float aw) {
#pragma unroll
  for (int o = 1; o < 16; o <<= 1) {
    ax += __shfl_xor(ax, o, 64); ay += __shfl_xor(ay, o, 64);
    az += __shfl_xor(az, o, 64); aw += __shfl_xor(aw, o, 64);
  }
  return make_float4(ax, ay, az, aw);
}

// One Horner half-step, 132 blocks: fb2 -> khalf = fb2&1, fb = fb2>>1,
// row r = fb>>1, cols jbase..jbase+255 (jbase = (fb&1)*256), k-range
// khalf*256..+256. Threads: 64 col-quads x 16 k-chunks of 16. float4 loads
// of Rm/Mt, acc[4] fp64/thread, LDS reduce. Inputs: previous level as a
// partial PAIR (Fpa+Fpb summed at load); output: this half's fp32 partial
// (khalf 0 carries the +cb term). Halves per-CU L1 traffic vs fstep66.
__device__ __forceinline__ void fstep132(
    int fb2, int tid, int first, const float* __restrict__ Fpa,
    const float* __restrict__ Fpb, const float* __restrict__ zbuf,
    const float* __restrict__ Rm, const float* __restrict__ Mt,
    float* __restrict__ Pa, float* __restrict__ Pb) {
  __shared__ float sA[256], sB[256];
  __shared__ double redm[16][256];
  const int khalf = fb2 & 1, fb = fb2 >> 1;
  const int r = fb >> 1, jbase = (fb & 1) * 256;
  const int rm = (r >= 8 && r < 32) ? (r - 8) : (r == 32 ? 32 : -1);
  const int kbase = khalf * 256;
  if (tid < 256) {
    int kk = kbase + tid;
    sA[tid] = first
        ? ((r < 8) ? zbuf[r * D + kk] : (r == 32 ? zbuf[8 * D + kk] : 0.f))
        : (Fpa[r * D + kk] + Fpb[r * D + kk]);
  } else if (tid < 512) {
    int kk = kbase + (tid - 256);
    float v = 0.f;
    if (rm >= 0)
      v = first ? ((rm < 8) ? zbuf[rm * D + kk]
                            : (rm == 32 ? zbuf[8 * D + kk] : 0.f))
                : (Fpa[rm * D + kk] + Fpb[rm * D + kk]);
    sB[tid - 256] = v;
  }
  __syncthreads();
  const int q = tid & 63, kc = tid >> 6;   // col-quad, k-chunk (16 x 16)
  const int j0 = jbase + q * 4, kl = kc * 16;
  double a0 = 0, a1 = 0, a2 = 0, a3 = 0;
#pragma unroll 2
  for (int k = 0; k < 16; ++k) {
    const size_t krow = (size_t)(kbase + kl + k) * D;
    const float4 rv = *(const float4*)(Rm + krow + j0);
    const float4 mv = *(const float4*)(Mt + krow + j0);
    const double a = (double)sA[kl + k], b = (double)sB[kl + k];
    a0 += a * (double)rv.x + b * (double)mv.x;
    a1 += a * (double)rv.y + b * (double)mv.y;
    a2 += a * (double)rv.z + b * (double)mv.z;
    a3 += a * (double)rv.w + b * (double)mv.w;
  }
  redm[kc][q * 4 + 0] = a0; redm[kc][q * 4 + 1] = a1;
  redm[kc][q * 4 + 2] = a2; redm[kc][q * 4 + 3] = a3;
  __syncthreads();
  if (tid < 256) {
    double s = 0.0;
#pragma unroll
    for (int u = 0; u < 16; ++u) s += redm[u][tid];
    int j = jbase + tid;
    float cb = 0.f;
    if (khalf == 0)
      cb = (r < 8) ? zbuf[r * D + j] : (r == 32 ? zbuf[8 * D + j] : 0.f);
    (khalf ? Pb : Pa)[r * D + j] = (float)(s + (double)cb);
  }
}

// ---- L0: knn normalize | geo (16 thr/pt) | pq(z) | Mt | Rm ----
// (verified round-2 form: broadcast/coalesced reads, scattered writes)
__global__ __launch_bounds__(256) void prep_kernel(
    const float* __restrict__ pts, const int* __restrict__ raw,
    const float* __restrict__ w_mlp1, const float* __restrict__ b_mlp1,
    const float* __restrict__ w_lfa1, const float* __restrict__ b_lfa1,
    const float* __restrict__ w_lfa2, const float* __restrict__ b_lfa2,
    const float* __restrict__ w_mlp2, const float* __restrict__ b_mlp2,
    const float* __restrict__ w_res, const float* __restrict__ b_res,
    int* __restrict__ knn_i, float4* __restrict__ sbase,
    float* __restrict__ zbuf, float* __restrict__ Mt,
    float* __restrict__ Rm) {
  // int64 little-endian => odd words are zero high halves; (1/16384)^4 FP risk
  const bool is64 = (raw[1] == 0) && (raw[3] == 0) && (raw[5] == 0) &&
                    (raw[7] == 0);
  const int t = blockIdx.x * 256 + threadIdx.x;  // < 262144 == D*D
  knn_i[t] = is64 ? raw[2 * t] : raw[t];
  {  // geo: 16 threads/point
    int n = t >> 4, k = t & 15;
    int idx = is64 ? raw[2 * (n * KNB + k)] : raw[n * KNB + k];
    float dx = pts[n * 3 + 0] - pts[idx * 3 + 0];
    float dy = pts[n * 3 + 1] - pts[idx * 3 + 1];
    float dz = pts[n * 3 + 2] - pts[idx * 3 + 2];
    float nr = sqrtf(dx * dx + dy * dy + dz * dz);
    float4 s = red16(dx, dy, dz, nr);
    if (k == 0) {
      const float r = 1.f / 16.f;
      sbase[n] = make_float4(s.x * r, s.y * r, s.z * r, s.w * r);
    }
  }
  if (t < 32768) {  // pq: one wave per output column j; fp64 accumulate
    int j = t >> 6, lane = t & 63;
    const float* wrow = w_mlp2 + (size_t)j * D;
    double acc[9];
#pragma unroll
    for (int u = 0; u < 9; ++u) acc[u] = 0.0;
#pragma unroll
    for (int it = 0; it < 8; ++it) {
      int i = lane + 64 * it;
      double w = wrow[i];
      if (i < 256) {
        acc[0] += w * w_lfa2[i * 4 + 0]; acc[1] += w * w_lfa2[i * 4 + 1];
        acc[2] += w * w_lfa2[i * 4 + 2]; acc[3] += w * w_lfa2[i * 4 + 3];
        acc[8] += w * b_lfa2[i];
      } else if (i < 384) {
        int q = i - 256;
        acc[4] += w * w_lfa1[q * 4 + 0]; acc[5] += w * w_lfa1[q * 4 + 1];
        acc[6] += w * w_lfa1[q * 4 + 2]; acc[7] += w * w_lfa1[q * 4 + 3];
        acc[8] += w * b_lfa1[q];
      } else {
        acc[8] += w * b_mlp1[i - 384];
      }
    }
#pragma unroll
    for (int u = 0; u < 9; ++u) {
      double v = acc[u];
#pragma unroll
      for (int o = 32; o > 0; o >>= 1) v += __shfl_down(v, o, 64);
      if (lane == 0) {
        if (u == 8) v += (double)b_mlp2[j] + (double)b_res[j];
        zbuf[u * D + j] = (float)v;
      }
    }
  }
  {  // Mt[a*D+b] = sum_{i<128} w_mlp2[b][384+i]*w_mlp1[i][a]  (fp64 acc)
    int a = t & 511, b = t >> 9;
    const float* wrow = w_mlp2 + (size_t)b * D + 384;
    double s0 = 0.0, s1 = 0.0, s2 = 0.0, s3 = 0.0;
#pragma unroll 8
    for (int i = 0; i < 128; i += 4) {
      s0 += (double)wrow[i + 0] * (double)w_mlp1[(size_t)(i + 0) * D + a];
      s1 += (double)wrow[i + 1] * (double)w_mlp1[(size_t)(i + 1) * D + a];
      s2 += (double)wrow[i + 2] * (double)w_mlp1[(size_t)(i + 2) * D + a];
      s3 += (double)wrow[i + 3] * (double)w_mlp1[(size_t)(i + 3) * D + a];
    }
    Mt[(size_t)a * D + b] = (float)((s0 + s1) + (s2 + s3));
  }
  {  // Rm[i*D+j] = w_res[j][i] + (i==j)
    int i = t & 511, j = t >> 9;
    Rm[(size_t)i * D + j] = w_res[(size_t)j * D + i] + ((i == j) ? 1.0f : 0.0f);
  }
}

// ---- combined: blocks [0,256) 1-hop (16 thr/pt), [256,388) fstep132 ----
__global__ __launch_bounds__(1024, 8) void hopf_kernel(
    const int* __restrict__ knn, const float4* __restrict__ sin,
    float4* __restrict__ sout, const float* __restrict__ zbuf,
    const float* __restrict__ Rm, const float* __restrict__ Mt,
    const float* __restrict__ Fpa, const float* __restrict__ Fpb,
    float* __restrict__ Pa, float* __restrict__ Pb, int first) {
  const int tid = threadIdx.x;
  if (blockIdx.x < 256) {
    onehop16(blockIdx.x * 1024 + tid, knn, sin, sout);
  } else {
    fstep132((int)blockIdx.x - 256, tid, first, Fpa, Fpb, zbuf, Rm, Mt,
             Pa, Pb);
  }
}

// ---- pure 1-hop: 256 blocks, 16 thr/pt, no LDS ----
__global__ __launch_bounds__(1024, 8) void hop_kernel(
    const int* __restrict__ knn, const float4* __restrict__ sin,
    float4* __restrict__ sout) {
  onehop16(blockIdx.x * 1024 + threadIdx.x, knn, sin, sout);
}

// ---- L4: out[n][:] = [s0..s7,1][n] x (Ea+Eb); s7 inline (1-hop from s6) ----
__global__ __launch_bounds__(1024, 4) void out_kernel(
    const int* __restrict__ knn, const float4* __restrict__ sbase,
    const float* __restrict__ Ea, const float* __restrict__ Eb,
    float* __restrict__ outp) {
  const int tid = threadIdx.x;
  const int n0 = blockIdx.x * 64;
  __shared__ float4 s_t[8][64];
  {  // s7 for this block's 64 points: 16 threads/point
    int pt = tid >> 4, k = tid & 15;
    float4 g = sbase[(size_t)6 * NPTS + knn[(n0 + pt) * KNB + k]];
    float4 s = red16(g.x, g.y, g.z, g.w);
    if (k == 0) {
      const float r = 1.f / 16.f;
      s_t[7][pt] = make_float4(s.x * r, s.y * r, s.z * r, s.w * r);
    }
  }
  if (tid < 448) {  // load s0..s6 tiles
    int k = tid / 64, pt = tid & 63;
    s_t[k][pt] = sbase[(size_t)k * NPTS + n0 + pt];
  }
  __syncthreads();
  const int col2 = tid & 255;  // this thread's float2 column
  const int ptg = tid >> 8;    // 0..3
  float2 tab[33];
#pragma unroll
  for (int r = 0; r < 33; ++r) {
    float2 pa = *(const float2*)(Ea + r * D + col2 * 2);
    float2 pb = *(const float2*)(Eb + r * D + col2 * 2);
    tab[r] = make_float2(pa.x + pb.x, pa.y + pb.y);
  }
#pragma unroll
  for (int it = 0; it < 16; ++it) {
    int pt = ptg * 16 + it;
    float2 acc = tab[32];
#pragma unroll
    for (int k = 0; k < 8; ++k) {
      float4 s = s_t[k][pt];  // wave-uniform LDS broadcast
      float2 e0 = tab[4 * k + 0], e1 = tab[4 * k + 1];
      float2 e2 = tab[4 * k + 2], e3 = tab[4 * k + 3];
      acc.x += s.x * e0.x + s.y * e1.x + s.z * e2.x + s.w * e3.x;
      acc.y += s.x * e0.y + s.y * e1.y + s.z * e2.y + s.w * e3.y;
    }
    *(float2*)(outp + (size_t)(n0 + pt) * D + col2 * 2) = acc;
  }
}

extern "C" void kernel_launch(void* const* d_in, const int* in_sizes, int n_in,
                              void* d_out, int out_size, void* d_ws,
                              size_t ws_size, hipStream_t stream) {
  const float* inputs = (const float*)d_in[0];
  const int* knn_raw  = (const int*)d_in[1];
  const float* w_mlp1 = (const float*)d_in[2];
  const float* b_mlp1 = (const float*)d_in[3];
  const float* w_lfa1 = (const float*)d_in[4];
  const float* b_lfa1 = (const float*)d_in[5];
  const float* w_lfa2 = (const float*)d_in[6];
  const float* b_lfa2 = (const float*)d_in[7];
  const float* w_mlp2 = (const float*)d_in[8];
  const float* b_mlp2 = (const float*)d_in[9];
  const float* w_res  = (const float*)d_in[10];
  const float* b_res  = (const float*)d_in[11];
  float* out = (float*)d_out;

  // workspace (floats): ~5.5 MB
  float*  ws    = (float*)d_ws;
  float4* sbase = (float4*)(ws + 0);          // 8 * 16384 float4
  float*  zbuf  = ws + 524288;                // 9 * 512
  float*  F2a   = ws + 528896;                // 33 * 512 (also Ea)
  float*  F2b   = ws + 545792;                // 33 * 512 (also Eb)
  float*  F3a   = ws + 562688;                // 33 * 512
  float*  F3b   = ws + 579584;                // 33 * 512
  int*    knn_i = (int*)(ws + 596480);        // 262144 ints
  float*  Mt    = ws + 858624;                // 262144 floats
  float*  Rm    = ws + 1120768;               // 262144 floats (end 1382912)

  prep_kernel<<<1024, 256, 0, stream>>>(inputs, knn_raw, w_mlp1, b_mlp1,
                                        w_lfa1, b_lfa1, w_lfa2, b_lfa2,
                                        w_mlp2, b_mlp2, w_res, b_res,
                                        knn_i, sbase, zbuf, Mt, Rm);
  float4* s0 = (float4*)sbase;
  // H1: s1 = S s0 | fstep1: (F2a,F2b) = step(Cb)
  hopf_kernel<<<388, 1024, 0, stream>>>(knn_i, s0, s0 + NPTS, zbuf, Rm, Mt,
                                        (const float*)nullptr,
                                        (const float*)nullptr, F2a, F2b, 1);
  // H2: s2 = S s1
  hop_kernel<<<256, 1024, 0, stream>>>(knn_i, s0 + NPTS, s0 + 2 * NPTS);
  // H3: s3 = S s2 | fstep2: (F3a,F3b) = step(F2a+F2b)
  hopf_kernel<<<388, 1024, 0, stream>>>(knn_i, s0 + 2 * NPTS, s0 + 3 * NPTS,
                                        zbuf, Rm, Mt, F2a, F2b, F3a, F3b, 0);
  // H4: s4 = S s3
  hop_kernel<<<256, 1024, 0, stream>>>(knn_i, s0 + 3 * NPTS, s0 + 4 * NPTS);
  // H5: s5 = S s4 | fstep3: (Ea,Eb) = step(F3a+F3b)  (aliases F2a,F2b)
  hopf_kernel<<<388, 1024, 0, stream>>>(knn_i, s0 + 4 * NPTS, s0 + 5 * NPTS,
                                        zbuf, Rm, Mt, F3a, F3b, F2a, F2b, 0);
  // H6: s6 = S s5
  hop_kernel<<<256, 1024, 0, stream>>>(knn_i, s0 + 5 * NPTS, s0 + 6 * NPTS);
  // L4: out (s7 inline), Ecat = Ea + Eb
  out_kernel<<<256, 1024, 0, stream>>>(knn_i, sbase, F2a, F2b, out);
}